// Round 5
// baseline (144.921 us; speedup 1.0000x reference)
//
#include <hip/hip_runtime.h>
#include <math.h>

#define NB 8192
#define DK 128
#define SPLITJ 16
#define JSPAN (NB / SPLITJ)   // 512
#define NJT (JSPAN / 32)      // 16 col-tiles of 32 per block
#define GRID_MINE (NB / 128 * SPLITJ)   // 1024 blocks

typedef __attribute__((ext_vector_type(8))) short short8;
typedef __attribute__((ext_vector_type(16))) float float16;

__device__ inline unsigned short f2bf(float f) {
    unsigned int x = __float_as_uint(f);
    unsigned int r = (x + 0x7fffu + ((x >> 16) & 1u)) >> 16;
    return (unsigned short)r;
}

// order-preserving float<->uint encode (for atomicMin/atomicMax on floats)
__device__ inline unsigned enc_f(float f) {
    unsigned u = __float_as_uint(f);
    return ((int)u < 0) ? ~u : (u | 0x80000000u);
}
__device__ inline float dec_f(unsigned u) {
    unsigned b = (u & 0x80000000u) ? (u & 0x7fffffffu) : ~u;
    return __uint_as_float(b);
}

// ---------- normalize -> bf16, pack meta = label*16+group, init reductions ----------
__global__ void norm_kernel(const float* __restrict__ emb, const int* __restrict__ labels,
                            const int* __restrict__ groups, unsigned short* __restrict__ xnb,
                            int* __restrict__ meta, unsigned* __restrict__ apu,
                            unsigned* __restrict__ anu, int* __restrict__ ticket) {
    int row  = blockIdx.x * 4 + (threadIdx.x >> 6);
    int lane = threadIdx.x & 63;
    float2 v = ((const float2*)(emb + (size_t)row * DK))[lane];
    float ss = v.x * v.x + v.y * v.y;
#pragma unroll
    for (int off = 32; off; off >>= 1) ss += __shfl_xor(ss, off, 64);
    float inv = 1.0f / fmaxf(sqrtf(ss), 1e-12f);
    ushort2 o;
    o.x = f2bf(v.x * inv);
    o.y = f2bf(v.y * inv);
    ((ushort2*)(xnb + (size_t)row * DK))[lane] = o;
    if (lane == 0) meta[row] = (labels[row] << 4) | groups[row];
    if (threadIdx.x < 4) {
        int r = blockIdx.x * 4 + threadIdx.x;
        apu[r] = 0xFFFFFFFFu;   // +inf for min
        anu[r] = 0u;            // -inf for max
    }
    if (blockIdx.x == 0 && threadIdx.x == 0) *ticket = 0;
}

// ---------- barrier-free MFMA gram + mining + ticketed finalize ----------
// Encoded epilogue: e = s + (same_label ? -16 : (same_group ? +4 : 0))
//   mn = min(e): same-label elems are <= -14.98, always win -> apS = mn + 16
//   mx = max(e): sg-negs in [2.98,5.02], other negs in [-1.02,1.02], positives <= -14.98
//   decode: anS = mx>2 ? mx-4 : mx ; loss = anS - mn - 15.9
//   sentinels: no diff-label -> mx<=-14.9 -> loss<0. Diag-in-ap same as r2-r4 (verified).
// C layout (verified): col = lane&31, row = (reg&3) + 8*(reg>>2) + 4*(lane>>5)
__global__ __launch_bounds__(256, 3) void mine_mfma(
    const unsigned short* __restrict__ xnb, const int* __restrict__ meta,
    unsigned* __restrict__ apu, unsigned* __restrict__ anu,
    int* __restrict__ ticket, float* __restrict__ out) {
    const int tid  = threadIdx.x;
    const int w    = tid >> 6;
    const int lane = tid & 63;
    const int half = lane >> 5;
    const int l31  = lane & 31;
    const int irow  = blockIdx.x * 128 + w * 32;
    const int jbase = blockIdx.y * JSPAN;

    // A fragments, full K=128 resident (8 x short8 = 64 VGPRs)
    short8 afrag[8];
#pragma unroll
    for (int ks = 0; ks < 8; ks++)
        afrag[ks] = *(const short8*)(xnb + (size_t)(irow + l31) * DK + ks * 16 + half * 8);

    int metaI[16];
    float mn[16], mx[16];
#pragma unroll
    for (int reg = 0; reg < 16; reg++) {
        int r = (reg & 3) + 8 * (reg >> 2) + 4 * half;
        metaI[reg] = meta[irow + r];
        mn[reg] = 1e9f; mx[reg] = -1e9f;
    }

    for (int jt = 0; jt < NJT; jt++) {
        const int j0 = jbase + jt * 32;
        const int mj = meta[j0 + l31];
        const unsigned short* bp = xnb + (size_t)(j0 + l31) * DK + half * 8;
        short8 b[8];
#pragma unroll
        for (int ks = 0; ks < 8; ks++) b[ks] = *(const short8*)(bp + ks * 16);

        float16 c;
#pragma unroll
        for (int e = 0; e < 16; e++) c[e] = 0.0f;
#pragma unroll
        for (int ks = 0; ks < 8; ks++)
            c = __builtin_amdgcn_mfma_f32_32x32x16_bf16(afrag[ks], b[ks], c, 0, 0, 0);

#pragma unroll
        for (int reg = 0; reg < 16; reg++) {
            float s = c[reg];
            int x = metaI[reg] ^ mj;
            bool sl = (unsigned)x < 16u;      // same label
            bool sg = (x & 15) == 0;          // same group (true superset incl. sl&&sg)
            float b0 = sg ? 4.0f : 0.0f;
            float bb = sl ? -16.0f : b0;
            float e  = s + bb;
            mn[reg] = fminf(mn[reg], e);
            mx[reg] = fmaxf(mx[reg], e);
        }
    }

    // butterfly reduce across the 32 column-lanes (offsets < 32 stay in-half)
#pragma unroll
    for (int reg = 0; reg < 16; reg++) {
#pragma unroll
        for (int off = 16; off; off >>= 1) {
            mn[reg] = fminf(mn[reg], __shfl_xor(mn[reg], off, 64));
            mx[reg] = fmaxf(mx[reg], __shfl_xor(mx[reg], off, 64));
        }
    }
    if (l31 == 0) {
#pragma unroll
        for (int reg = 0; reg < 16; reg++) {
            int r = (reg & 3) + 8 * (reg >> 2) + 4 * half;
            atomicMin(&apu[irow + r], enc_f(mn[reg]));
            atomicMax(&anu[irow + r], enc_f(mx[reg]));
        }
    }

    // ---------- ticketed finalize by the last-finishing block ----------
    __shared__ float ssum[4], scnt[4];
    __shared__ int lastFlag;
    __syncthreads();                      // drains this block's atomics (vmcnt)
    if (tid == 0) {
        __threadfence();
        int old = atomicAdd(ticket, 1);   // device-scope
        lastFlag = (old == GRID_MINE - 1);
    }
    __syncthreads();
    if (!lastFlag) return;
    __threadfence();                      // acquire: invalidate stale cached lines

    float s = 0.0f, ccnt = 0.0f;
#pragma unroll
    for (int k = 0; k < NB / 256; k++) {
        int i = tid + k * 256;
        float mnf = dec_f(apu[i]);
        float mxf = dec_f(anu[i]);
        float anS = (mxf > 2.0f) ? mxf - 4.0f : mxf;
        float loss = anS - mnf - 15.9f;   // anS - (mnf+16) + 0.1
        if (loss > 0.0f) { s += loss; ccnt += 1.0f; }
    }
#pragma unroll
    for (int off = 32; off; off >>= 1) {
        s    += __shfl_xor(s, off, 64);
        ccnt += __shfl_xor(ccnt, off, 64);
    }
    if (lane == 0) { ssum[w] = s; scnt[w] = ccnt; }
    __syncthreads();
    if (tid == 0) {
        float ts = 0.f, tc = 0.f;
#pragma unroll
        for (int wv = 0; wv < 4; wv++) { ts += ssum[wv]; tc += scnt[wv]; }
        float r = (tc > 0.0f) ? ts / fmaxf(tc, 1.0f) : 0.0f;
        if (isnan(r)) r = 0.0f;
        out[0] = r;
    }
}

extern "C" void kernel_launch(void* const* d_in, const int* in_sizes, int n_in,
                              void* d_out, int out_size, void* d_ws, size_t ws_size,
                              hipStream_t stream) {
    const float* emb  = (const float*)d_in[0];
    const int* labels = (const int*)d_in[1];
    const int* groups = (const int*)d_in[2];
    float* out = (float*)d_out;

    unsigned short* xnb = (unsigned short*)d_ws;        // 2 MB
    int*      meta   = (int*)(xnb + (size_t)NB * DK);   // 32 KB
    unsigned* apu    = (unsigned*)(meta + NB);          // 32 KB
    unsigned* anu    = apu + NB;                        // 32 KB
    int*      ticket = (int*)(anu + NB);                // 4 B

    norm_kernel<<<NB / 4, 256, 0, stream>>>(emb, labels, groups, xnb, meta, apu, anu, ticket);
    mine_mfma<<<dim3(NB / 128, SPLITJ), 256, 0, stream>>>(xnb, meta, apu, anu, ticket, out);
}

// Round 6
// 118.321 us; speedup vs baseline: 1.2248x; 1.2248x over previous
//
#include <hip/hip_runtime.h>
#include <math.h>

#define NB 8192
#define DK 128
#define SPLITJ 16
#define JSPAN (NB / SPLITJ)   // 512
#define JT 64                 // j-rows per LDS tile
#define NT (JSPAN / JT)       // 8 tiles per block
#define GRID_MINE ((NB / 128) * SPLITJ)   // 1024 blocks

typedef __attribute__((ext_vector_type(8))) short short8;
typedef __attribute__((ext_vector_type(16))) float float16;
typedef __attribute__((address_space(3))) unsigned lds_u32;
typedef __attribute__((address_space(1))) const unsigned g_u32;

__device__ inline unsigned short f2bf(float f) {
    unsigned int x = __float_as_uint(f);
    unsigned int r = (x + 0x7fffu + ((x >> 16) & 1u)) >> 16;
    return (unsigned short)r;
}

// order-preserving float<->uint encode (for atomicMin/atomicMax on floats)
__device__ inline unsigned enc_f(float f) {
    unsigned u = __float_as_uint(f);
    return ((int)u < 0) ? ~u : (u | 0x80000000u);
}
__device__ inline float dec_f(unsigned u) {
    unsigned b = (u & 0x80000000u) ? (u & 0x7fffffffu) : ~u;
    return __uint_as_float(b);
}

// ---------- normalize -> bf16, pack meta = (label<<4)|group, init reductions ----------
__global__ void norm_kernel(const float* __restrict__ emb, const int* __restrict__ labels,
                            const int* __restrict__ groups, unsigned short* __restrict__ xnb,
                            int* __restrict__ meta, unsigned* __restrict__ apu,
                            unsigned* __restrict__ anu, int* __restrict__ ticket) {
    int row  = blockIdx.x * 4 + (threadIdx.x >> 6);
    int lane = threadIdx.x & 63;
    float2 v = ((const float2*)(emb + (size_t)row * DK))[lane];
    float ss = v.x * v.x + v.y * v.y;
#pragma unroll
    for (int off = 32; off; off >>= 1) ss += __shfl_xor(ss, off, 64);
    float inv = 1.0f / fmaxf(sqrtf(ss), 1e-12f);
    ushort2 o;
    o.x = f2bf(v.x * inv);
    o.y = f2bf(v.y * inv);
    ((ushort2*)(xnb + (size_t)row * DK))[lane] = o;
    if (lane == 0) meta[row] = (labels[row] << 4) | groups[row];
    if (threadIdx.x < 4) {
        int r = blockIdx.x * 4 + threadIdx.x;
        apu[r] = 0xFFFFFFFFu;   // +inf for min
        anu[r] = 0u;            // -inf for max
    }
    if (blockIdx.x == 0 && threadIdx.x == 0) *ticket = 0;
}

// ---------- MFMA gram + mining: global_load_lds dbuf staging, XOR-swizzled LDS ----------
// LDS tile: row-major, row stride 256 B (unpadded, required by DMA contiguity).
// Swizzle: 16-B chunk c of row r stored at slot c ^ (r & 15).
//   write: lane supplies permuted GLOBAL address (union stays 4 contiguous rows);
//   read:  slot = (ks*2) ^ q, q = (l31&15) ^ half  -> banks 2-way max (free, m136).
// Encoded epilogue: e = s + (same_label ? -16 : (same_group ? +4 : 0))
//   mn=min(e) -> apS = mn+16 ; mx=max(e) -> anS = mx>2 ? mx-4 : mx ; loss = anS-mn-15.9
// C layout (verified): col = lane&31, row = (reg&3) + 8*(reg>>2) + 4*(lane>>5)
__global__ __launch_bounds__(256, 3) void mine_mfma(
    const unsigned short* __restrict__ xnb, const int* __restrict__ meta,
    unsigned* __restrict__ apu, unsigned* __restrict__ anu,
    int* __restrict__ ticket, float* __restrict__ out) {
    __shared__ unsigned short Bs[2][JT * 128];   // 2 x 16 KB

    const int tid  = threadIdx.x;
    const int w    = tid >> 6;
    const int lane = tid & 63;
    const int half = lane >> 5;
    const int l31  = lane & 31;
    const int irow  = blockIdx.x * 128 + w * 32;
    const int jbase = blockIdx.y * JSPAN;

    // A fragments, full K=128 resident (8 x short8 = 64 VGPRs)
    short8 afrag[8];
#pragma unroll
    for (int ks = 0; ks < 8; ks++)
        afrag[ks] = *(const short8*)(xnb + (size_t)(irow + l31) * DK + ks * 16 + half * 8);

    int metaI[16];
    float mn[16], mx[16];
#pragma unroll
    for (int reg = 0; reg < 16; reg++) {
        int r = (reg & 3) + 8 * (reg >> 2) + 4 * half;
        metaI[reg] = meta[irow + r];
        mn[reg] = 1e9f; mx[reg] = -1e9f;
    }

    // staging per-lane source byte-offsets (swizzled), s = 0..3; wave w stages rows w*16..w*16+15
    int soff[4];
#pragma unroll
    for (int s = 0; s < 4; s++) {
        int r = w * 16 + s * 4 + (lane >> 4);          // row within tile
        int c = (lane & 15) ^ (r & 15);                // global chunk for this LDS slot
        soff[s] = r * 256 + c * 16;
    }
    const char* xb = (const char*)xnb;
    const int q = (l31 & 15) ^ half;                   // read-swizzle key (same for both ct)

#define STAGE(buf, j0)                                                            \
    {                                                                             \
        _Pragma("unroll")                                                         \
        for (int s = 0; s < 4; s++) {                                             \
            const void* g = xb + (size_t)(j0) * 256 + soff[s];                    \
            unsigned short* lp = &Bs[buf][(w * 4 + s) * 512];                     \
            __builtin_amdgcn_global_load_lds((g_u32*)g, (lds_u32*)lp, 16, 0, 0);  \
        }                                                                         \
    }

    STAGE(0, jbase);
    __syncthreads();

    for (int jt = 0; jt < NT; jt++) {
        const int buf = jt & 1;
        const int j0  = jbase + jt * JT;
        if (jt + 1 < NT) STAGE(buf ^ 1, j0 + JT);      // async DMA overlaps compute below

        int mjc[2];
        mjc[0] = meta[j0 + l31];
        mjc[1] = meta[j0 + 32 + l31];

#pragma unroll
        for (int ct = 0; ct < 2; ct++) {
            const unsigned short* base = &Bs[buf][(ct * 32 + l31) * 128];
            float16 c;
#pragma unroll
            for (int e = 0; e < 16; e++) c[e] = 0.0f;
#pragma unroll
            for (int ks = 0; ks < 8; ks++) {
                int slot = (ks * 2) ^ q;
                short8 b = *(const short8*)(base + slot * 8);
                c = __builtin_amdgcn_mfma_f32_32x32x16_bf16(afrag[ks], b, c, 0, 0, 0);
            }

            const int mj = mjc[ct];
#pragma unroll
            for (int reg = 0; reg < 16; reg++) {
                float s = c[reg];
                int x = metaI[reg] ^ mj;
                bool sl = (unsigned)x < 16u;      // same label
                bool sg = (x & 15) == 0;          // same group
                float b0 = sg ? 4.0f : 0.0f;
                float bb = sl ? -16.0f : b0;
                float e  = s + bb;
                mn[reg] = fminf(mn[reg], e);
                mx[reg] = fmaxf(mx[reg], e);
            }
        }
        __syncthreads();   // drains next-tile DMA (vmcnt) + protects buf reuse
    }

    // butterfly reduce across the 32 column-lanes (offsets < 32 stay in-half)
#pragma unroll
    for (int reg = 0; reg < 16; reg++) {
#pragma unroll
        for (int off = 16; off; off >>= 1) {
            mn[reg] = fminf(mn[reg], __shfl_xor(mn[reg], off, 64));
            mx[reg] = fmaxf(mx[reg], __shfl_xor(mx[reg], off, 64));
        }
    }
    if (l31 == 0) {
#pragma unroll
        for (int reg = 0; reg < 16; reg++) {
            int r = (reg & 3) + 8 * (reg >> 2) + 4 * half;
            atomicMin(&apu[irow + r], enc_f(mn[reg]));
            atomicMax(&anu[irow + r], enc_f(mx[reg]));
        }
    }

    // ---------- ticketed finalize by the last-finishing block ----------
    __shared__ float ssum[4], scnt[4];
    __shared__ int lastFlag;
    __syncthreads();
    if (tid == 0) {
        __threadfence();
        int old = atomicAdd(ticket, 1);   // device-scope
        lastFlag = (old == GRID_MINE - 1);
    }
    __syncthreads();
    if (!lastFlag) return;
    __threadfence();

    float s = 0.0f, ccnt = 0.0f;
#pragma unroll
    for (int k = 0; k < NB / 256; k++) {
        int i = tid + k * 256;
        float mnf = dec_f(apu[i]);
        float mxf = dec_f(anu[i]);
        float anS = (mxf > 2.0f) ? mxf - 4.0f : mxf;
        float loss = anS - mnf - 15.9f;   // anS - (mnf+16) + 0.1
        if (loss > 0.0f) { s += loss; ccnt += 1.0f; }
    }
#pragma unroll
    for (int off = 32; off; off >>= 1) {
        s    += __shfl_xor(s, off, 64);
        ccnt += __shfl_xor(ccnt, off, 64);
    }
    if (lane == 0) { ssum[w] = s; scnt[w] = ccnt; }
    __syncthreads();
    if (tid == 0) {
        float ts = 0.f, tc = 0.f;
#pragma unroll
        for (int wv = 0; wv < 4; wv++) { ts += ssum[wv]; tc += scnt[wv]; }
        float r = (tc > 0.0f) ? ts / fmaxf(tc, 1.0f) : 0.0f;
        if (isnan(r)) r = 0.0f;
        out[0] = r;
    }
}

extern "C" void kernel_launch(void* const* d_in, const int* in_sizes, int n_in,
                              void* d_out, int out_size, void* d_ws, size_t ws_size,
                              hipStream_t stream) {
    const float* emb  = (const float*)d_in[0];
    const int* labels = (const int*)d_in[1];
    const int* groups = (const int*)d_in[2];
    float* out = (float*)d_out;

    unsigned short* xnb = (unsigned short*)d_ws;        // 2 MB
    int*      meta   = (int*)(xnb + (size_t)NB * DK);   // 32 KB
    unsigned* apu    = (unsigned*)(meta + NB);          // 32 KB
    unsigned* anu    = apu + NB;                        // 32 KB
    int*      ticket = (int*)(anu + NB);                // 4 B

    norm_kernel<<<NB / 4, 256, 0, stream>>>(emb, labels, groups, xnb, meta, apu, anu, ticket);
    mine_mfma<<<dim3(NB / 128, SPLITJ), 256, 0, stream>>>(xnb, meta, apu, anu, ticket, out);
}